// Round 2
// baseline (392.055 us; speedup 1.0000x reference)
//
#include <hip/hip_runtime.h>

// src [2,2,160,192,160] f32, flow [2,3,160,192,160] f32, out [2,2,160,192,160] f32
#define BB 2
#define CC 2
#define DD 160
#define HH 192
#define WW 160
#define NN (DD * HH * WW)

// 8-byte vector with 4-byte alignment: the x-corner pair load is only
// dword-aligned (xb can be odd). ext_vector_type + aligned(4) keeps the
// load well-defined; AMDGPU emits a single global_load_dwordx2 regardless
// (unaligned global access is supported on gfx950).
typedef float f2u __attribute__((ext_vector_type(2), aligned(4)));

__global__ __launch_bounds__(256) void st_warp3d_kernel(
    const float* __restrict__ src,
    const float* __restrict__ flow,
    float* __restrict__ out)
{
    const int tid = blockIdx.x * blockDim.x + threadIdx.x;
    const int total = BB * NN;  // 9,830,400
    if (tid >= total) return;

    const int b = (tid >= NN) ? 1 : 0;
    const int n = tid - b * NN;
    const int x = n % WW;
    const int t = n / WW;
    const int y = t % HH;
    const int z = t / HH;

    const float* fl = flow + (size_t)b * 3 * NN + n;
    const float zc = (float)z + __builtin_nontemporal_load(fl);
    const float yc = (float)y + __builtin_nontemporal_load(fl + NN);
    const float xc = (float)x + __builtin_nontemporal_load(fl + 2 * (size_t)NN);

    const float z0f = floorf(zc), y0f = floorf(yc), x0f = floorf(xc);
    const float fz = zc - z0f, fy = yc - y0f, fx = xc - x0f;
    const int z0 = (int)z0f, y0 = (int)y0f, x0 = (int)x0f;
    const int z1 = z0 + 1, y1 = y0 + 1, x1 = x0 + 1;

    // per-axis weights with out-of-bounds masking folded in (zero-padding)
    const float wz0 = (z0 >= 0 && z0 < DD) ? (1.0f - fz) : 0.0f;
    const float wz1 = (z1 >= 0 && z1 < DD) ? fz : 0.0f;
    const float wy0 = (y0 >= 0 && y0 < HH) ? (1.0f - fy) : 0.0f;
    const float wy1 = (y1 >= 0 && y1 < HH) ? fy : 0.0f;
    const float wx0 = (x0 >= 0 && x0 < WW) ? (1.0f - fx) : 0.0f;
    const float wx1 = (x1 >= 0 && x1 < WW) ? fx : 0.0f;

    // clamped indices (safe addresses; OOB corners have weight 0)
    const int z0c = min(max(z0, 0), DD - 1);
    const int z1c = min(max(z1, 0), DD - 1);
    const int y0c = min(max(y0, 0), HH - 1);
    const int y1c = min(max(y1, 0), HH - 1);
    const int x0c = min(max(x0, 0), WW - 1);
    const int x1c = min(max(x1, 0), WW - 1);

    // pair base: both x0c and x1c lie in {xb, xb+1}, and [xb, xb+1] never
    // leaves the row -> one dwordx2 fetches both x-corners of every row.
    const int xb = min(max(x0, 0), WW - 2);

    // fold the x-corner selection into the PAIR weights (computed once):
    //   q0 weights element at xb, q1 weights element at xb+1
    const float q0 = (x0c == xb ? wx0 : 0.0f) + (x1c == xb ? wx1 : 0.0f);
    const float q1 = (wx0 + wx1) - q0;

    // 4 row bases (pair-adjusted)
    const int r00 = (z0c * HH + y0c) * WW + xb;
    const int r01 = (z0c * HH + y1c) * WW + xb;
    const int r10 = (z1c * HH + y0c) * WW + xb;
    const int r11 = (z1c * HH + y1c) * WW + xb;

    const float* s0 = src + (size_t)b * CC * NN;  // channel 0
    const float* s1 = s0 + NN;                    // channel 1

    // issue all 8 pair-gathers up front — independent, one waitcnt
    const f2u a00 = *(const f2u*)(s0 + r00);
    const f2u a01 = *(const f2u*)(s0 + r01);
    const f2u a10 = *(const f2u*)(s0 + r10);
    const f2u a11 = *(const f2u*)(s0 + r11);
    const f2u b00 = *(const f2u*)(s1 + r00);
    const f2u b01 = *(const f2u*)(s1 + r01);
    const f2u b10 = *(const f2u*)(s1 + r10);
    const f2u b11 = *(const f2u*)(s1 + r11);

    const float w00 = wz0 * wy0, w01 = wz0 * wy1, w10 = wz1 * wy0, w11 = wz1 * wy1;
    // 8 corner weights (shared by both channels)
    const float w00q0 = w00 * q0, w00q1 = w00 * q1;
    const float w01q0 = w01 * q0, w01q1 = w01 * q1;
    const float w10q0 = w10 * q0, w10q1 = w10 * q1;
    const float w11q0 = w11 * q0, w11q1 = w11 * q1;

    const float acc0 = a00.x * w00q0 + a00.y * w00q1 +
                       a01.x * w01q0 + a01.y * w01q1 +
                       a10.x * w10q0 + a10.y * w10q1 +
                       a11.x * w11q0 + a11.y * w11q1;
    const float acc1 = b00.x * w00q0 + b00.y * w00q1 +
                       b01.x * w01q0 + b01.y * w01q1 +
                       b10.x * w10q0 + b10.y * w10q1 +
                       b11.x * w11q0 + b11.y * w11q1;

    float* o = out + (size_t)b * CC * NN + n;
    __builtin_nontemporal_store(acc0, o);
    __builtin_nontemporal_store(acc1, o + NN);
}

extern "C" void kernel_launch(void* const* d_in, const int* in_sizes, int n_in,
                              void* d_out, int out_size, void* d_ws, size_t ws_size,
                              hipStream_t stream) {
    const float* src  = (const float*)d_in[0];
    const float* flow = (const float*)d_in[1];
    float* out = (float*)d_out;

    const int total = BB * NN;
    const int block = 256;
    const int grid = (total + block - 1) / block;

    st_warp3d_kernel<<<grid, block, 0, stream>>>(src, flow, out);
}

// Round 3
// 290.565 us; speedup vs baseline: 1.3493x; 1.3493x over previous
//
#include <hip/hip_runtime.h>

// src [2,2,160,192,160] f32, flow [2,3,160,192,160] f32, out [2,2,160,192,160] f32
#define BB 2
#define CC 2
#define DD 160
#define HH 192
#define WW 160
#define HW_ (HH * WW)
#define NN (DD * HW_)

// tile geometry: block = 32x8 voxels, loops CZ z-planes; LDS ring of SLOTS plane-slabs
#define TX 32
#define TY 8
#define CZ 20
#define HALO 4
#define SLOTS 10
#define ROWS (TY + 2 * HALO)          // 16 staged rows (y)
#define RSTR (TX + 2 * HALO)          // 40 floats per staged row (x)
#define PLANE_CH (RSTR * ROWS)        // 640 floats per plane per channel
#define PLANE_LDS (PLANE_CH * CC)     // 1280 floats per ring slot
// LDS total = SLOTS*PLANE_LDS*4 = 51,200 B -> 3 blocks/CU (150 KB <= 160 KB)

// 8-byte vector with 4-byte alignment (fallback path pair loads)
typedef float f2u __attribute__((ext_vector_type(2), aligned(4)));

__global__ __launch_bounds__(256) void st_warp3d_tiled(
    const float* __restrict__ src,
    const float* __restrict__ flow,
    float* __restrict__ out)
{
    const int tid = threadIdx.x;
    const int tx = tid & (TX - 1);
    const int ty = tid >> 5;

    const int tile = blockIdx.x;              // 0..119 : 5 x-tiles * 24 y-tiles
    const int Xo = (tile % 5) * TX;
    const int Yo = (tile / 5) * TY;
    const int Z0 = blockIdx.y * CZ;           // 8 z-chunks
    const int b  = blockIdx.z;                // batch

    const int x = Xo + tx;
    const int y = Yo + ty;

    // staged ranges, clipped to the volume (uniform per block).
    // Reads use clamped coords, which always land inside the clipped range,
    // so staged rows are contiguous in-bounds segments (no elementwise clamp).
    const int sxlo = max(Xo - HALO, 0);
    const int sxhi = min(Xo + TX + HALO, WW);
    const int Ws   = sxhi - sxlo;             // 36 or 40 (always mult of 4)
    const int sylo = max(Yo - HALO, 0);
    const int syhi = min(Yo + TY + HALO, HH);
    const int Rs   = syhi - sylo;             // 12..16

    __shared__ float lds[SLOTS * PLANE_LDS];

    const float* __restrict__ sbase = src + (size_t)b * CC * NN;

    // --- staging job precompute: 320 float4 slots per plane (2ch x 16row x 10),
    //     job A = slot tid, job B = slot tid+256 (threads 0..63 only)
    int goffA = 0, loffA = 0; bool vA;
    {
        const int s  = tid;                    // 0..255
        const int ch = (s >= 160) ? 1 : 0;     // 160 slots per channel
        const int r  = s - ch * 160;           // 0..159
        const int yy = r / 10;
        const int xs = r - yy * 10;
        vA    = (yy < Rs) && (xs * 4 < Ws);
        goffA = ch * NN + (sylo + yy) * WW + sxlo + xs * 4;
        loffA = ch * PLANE_CH + yy * RSTR + xs * 4;
    }
    int goffB = 0, loffB = 0; bool vB = false;
    if (tid < 64) {
        const int s  = tid + 256;              // 256..319 -> ch1, rows 9..15
        const int r  = s - 160;
        const int yy = r / 10;
        const int xs = r - yy * 10;
        vB    = (yy < Rs) && (xs * 4 < Ws);
        goffB = NN + (sylo + yy) * WW + sxlo + xs * 4;
        loffB = PLANE_CH + yy * RSTR + xs * 4;
    }

    // --- prologue: stage planes [max(Z0-4,0), min(Z0+4,D-1)] into ring slots q%SLOTS
    const int qlo  = max(Z0 - HALO, 0);
    const int qhi0 = min(Z0 + HALO, DD - 1);
    for (int qq = qlo; qq <= qhi0; ++qq) {
        const float* gp = sbase + (size_t)qq * HW_;
        float* lp = lds + (qq % SLOTS) * PLANE_LDS;
        if (vA) *(float4*)(lp + loffA) = *(const float4*)(gp + goffA);
        if (vB) *(float4*)(lp + loffB) = *(const float4*)(gp + goffB);
    }
    const int qmax = min(DD - 1, Z0 + CZ - 1 + HALO);

    const size_t fbase = (size_t)b * 3 * NN + (size_t)y * WW + x;
    const size_t obase = (size_t)b * CC * NN + (size_t)y * WW + x;

    for (int z = Z0; z < Z0 + CZ; ++z) {
        __syncthreads();   // staged plane z+4 visible; all waves done with plane z-5's slot

        // T14 split: issue next-plane (z+5) loads now; ds_write after compute
        const int qp = z + HALO + 1;
        const bool pre = (qp <= qmax);
        float4 pA, pB;
        if (pre) {
            const float* gp = sbase + (size_t)qp * HW_;
            if (vA) pA = *(const float4*)(gp + goffA);
            if (vB) pB = *(const float4*)(gp + goffB);
        }

        // --- flow + weights (shared by LDS path and fallback)
        const float* fl = flow + fbase + (size_t)z * HW_;
        const float fzv = __builtin_nontemporal_load(fl);
        const float fyv = __builtin_nontemporal_load(fl + NN);
        const float fxv = __builtin_nontemporal_load(fl + 2 * (size_t)NN);
        const float zc = (float)z + fzv;
        const float yc = (float)y + fyv;
        const float xc = (float)x + fxv;

        const float z0f = floorf(zc), y0f = floorf(yc), x0f = floorf(xc);
        const float fz = zc - z0f, fy = yc - y0f, fx = xc - x0f;
        const int z0 = (int)z0f, y0 = (int)y0f, x0 = (int)x0f;
        const int z1 = z0 + 1, y1 = y0 + 1, x1 = x0 + 1;

        const float wz0 = (z0 >= 0 && z0 < DD) ? (1.0f - fz) : 0.0f;
        const float wz1 = (z1 >= 0 && z1 < DD) ? fz : 0.0f;
        const float wy0 = (y0 >= 0 && y0 < HH) ? (1.0f - fy) : 0.0f;
        const float wy1 = (y1 >= 0 && y1 < HH) ? fy : 0.0f;
        const float wx0 = (x0 >= 0 && x0 < WW) ? (1.0f - fx) : 0.0f;
        const float wx1 = (x1 >= 0 && x1 < WW) ? fx : 0.0f;

        const int z0c = min(max(z0, 0), DD - 1), z1c = min(max(z1, 0), DD - 1);
        const int y0c = min(max(y0, 0), HH - 1), y1c = min(max(y1, 0), HH - 1);
        const int x0c = min(max(x0, 0), WW - 1), x1c = min(max(x1, 0), WW - 1);
        const int xb  = min(max(x0, 0), WW - 2);

        const float q0 = (x0c == xb ? wx0 : 0.0f) + (x1c == xb ? wx1 : 0.0f);
        const float q1 = (wx0 + wx1) - q0;
        const float w00 = wz0 * wy0, w01 = wz0 * wy1, w10 = wz1 * wy0, w11 = wz1 * wy1;
        const float w00q0 = w00 * q0, w00q1 = w00 * q1;
        const float w01q0 = w01 * q0, w01q1 = w01 * q1;
        const float w10q0 = w10 * q0, w10q1 = w10 * q1;
        const float w11q0 = w11 * q0, w11q1 = w11 * q1;

        // in-tile iff floor(flow) in [-4,3] on all axes (P(out) ~ 2e-4/voxel)
        const int dzi = z0 - z, dyi = y0 - y, dxi = x0 - x;
        const bool inTile = ((unsigned)(dzi + HALO) <= 7u) &&
                            ((unsigned)(dyi + HALO) <= 7u) &&
                            ((unsigned)(dxi + HALO) <= 7u);

        float acc0, acc1;
        if (inTile) {
            const int slot0 = z0c % SLOTS;
            const int slot1 = z1c % SLOTS;
            const int yi0 = y0c - sylo, yi1 = y1c - sylo;
            const int xi  = xb - sxlo;
            const int i00 = slot0 * PLANE_LDS + yi0 * RSTR + xi;
            const int i01 = slot0 * PLANE_LDS + yi1 * RSTR + xi;
            const int i10 = slot1 * PLANE_LDS + yi0 * RSTR + xi;
            const int i11 = slot1 * PLANE_LDS + yi1 * RSTR + xi;

            const float a00x = lds[i00],            a00y = lds[i00 + 1];
            const float a01x = lds[i01],            a01y = lds[i01 + 1];
            const float a10x = lds[i10],            a10y = lds[i10 + 1];
            const float a11x = lds[i11],            a11y = lds[i11 + 1];
            const float b00x = lds[i00 + PLANE_CH], b00y = lds[i00 + PLANE_CH + 1];
            const float b01x = lds[i01 + PLANE_CH], b01y = lds[i01 + PLANE_CH + 1];
            const float b10x = lds[i10 + PLANE_CH], b10y = lds[i10 + PLANE_CH + 1];
            const float b11x = lds[i11 + PLANE_CH], b11y = lds[i11 + PLANE_CH + 1];

            acc0 = a00x * w00q0 + a00y * w00q1 + a01x * w01q0 + a01y * w01q1 +
                   a10x * w10q0 + a10y * w10q1 + a11x * w11q0 + a11y * w11q1;
            acc1 = b00x * w00q0 + b00y * w00q1 + b01x * w01q0 + b01y * w01q1 +
                   b10x * w10q0 + b10y * w10q1 + b11x * w11q0 + b11y * w11q1;
        } else {
            // rare outlier: direct global gather (identical math to prev kernel)
            const int r00 = (z0c * HH + y0c) * WW + xb;
            const int r01 = (z0c * HH + y1c) * WW + xb;
            const int r10 = (z1c * HH + y0c) * WW + xb;
            const int r11 = (z1c * HH + y1c) * WW + xb;
            const float* s1p = sbase + NN;
            const f2u a00 = *(const f2u*)(sbase + r00);
            const f2u a01 = *(const f2u*)(sbase + r01);
            const f2u a10 = *(const f2u*)(sbase + r10);
            const f2u a11 = *(const f2u*)(sbase + r11);
            const f2u c00 = *(const f2u*)(s1p + r00);
            const f2u c01 = *(const f2u*)(s1p + r01);
            const f2u c10 = *(const f2u*)(s1p + r10);
            const f2u c11 = *(const f2u*)(s1p + r11);
            acc0 = a00.x * w00q0 + a00.y * w00q1 + a01.x * w01q0 + a01.y * w01q1 +
                   a10.x * w10q0 + a10.y * w10q1 + a11.x * w11q0 + a11.y * w11q1;
            acc1 = c00.x * w00q0 + c00.y * w00q1 + c01.x * w01q0 + c01.y * w01q1 +
                   c10.x * w10q0 + c10.y * w10q1 + c11.x * w11q0 + c11.y * w11q1;
        }

        float* o = out + obase + (size_t)z * HW_;
        __builtin_nontemporal_store(acc0, o);
        __builtin_nontemporal_store(acc1, o + NN);

        // late ds_write of prefetched plane (slot (z+5)%SLOTS is not read by step z)
        if (pre) {
            float* lp = lds + (qp % SLOTS) * PLANE_LDS;
            if (vA) *(float4*)(lp + loffA) = pA;
            if (vB) *(float4*)(lp + loffB) = pB;
        }
    }
}

extern "C" void kernel_launch(void* const* d_in, const int* in_sizes, int n_in,
                              void* d_out, int out_size, void* d_ws, size_t ws_size,
                              hipStream_t stream) {
    const float* src  = (const float*)d_in[0];
    const float* flow = (const float*)d_in[1];
    float* out = (float*)d_out;

    dim3 grid(5 * 24, DD / CZ, BB);   // 120 xy-tiles, 8 z-chunks, 2 batches = 1920 blocks
    dim3 block(256);
    st_warp3d_tiled<<<grid, block, 0, stream>>>(src, flow, out);
}

// Round 5
// 267.595 us; speedup vs baseline: 1.4651x; 1.0858x over previous
//
#include <hip/hip_runtime.h>

// src [2,2,160,192,160] f32, flow [2,3,160,192,160] f32, out [2,2,160,192,160] f32
#define BB 2
#define CC 2
#define DD 160
#define HH 192
#define WW 160
#define HW_ (HH * WW)
#define NN (DD * HW_)

// tile geometry: block = 32x16 voxels (512 thr), loops CZ z-planes
// LDS ring: SLOTS plane-slabs; depth-2 prefetch (issue @ z-1, ds_write @ z, read @ z+1)
#define TX 32
#define TY 16
#define CZ 20
#define HX 4                           // x halo (keeps float4 staging aligned)
#define HY 3
#define HZ 4
#define SLOTS 11                       // read window 10 planes [z-4, z+5] + 1 write slot
#define ROWS (TY + 2 * HY)             // 22 staged rows (y)
#define RSTR (TX + 2 * HX)             // 40 floats per staged row (x)
#define PLANE_CH (RSTR * ROWS)         // 880 floats per plane per channel
#define PLANE_LDS (PLANE_CH * CC)      // 1760 floats per ring slot
// LDS total = 11*1760*4 = 77,440 B -> 2 blocks/CU (154.9 KB <= 160 KB), 16 waves = 50%

// 8-byte vector with 4-byte alignment (fallback path pair loads)
typedef float f2u __attribute__((ext_vector_type(2), aligned(4)));

__global__ __launch_bounds__(512, 4) void st_warp3d_tiled2(
    const float* __restrict__ src,
    const float* __restrict__ flow,
    float* __restrict__ out)
{
    const int tid = threadIdx.x;
    const int tx = tid & (TX - 1);
    const int ty = tid >> 5;                  // 0..15

    const int tile = blockIdx.x;              // 0..59 : 5 x-tiles * 12 y-tiles
    const int Xo = (tile % 5) * TX;
    const int Yo = (tile / 5) * TY;
    const int Z0 = blockIdx.y * CZ;           // 8 z-chunks
    const int b  = blockIdx.z;                // batch

    const int x = Xo + tx;
    const int y = Yo + ty;

    // staged ranges, clipped to the volume (block-uniform). Clamped sample
    // coords passing the in-tile test always land inside these ranges.
    const int sxlo = max(Xo - HX, 0);
    const int sxhi = min(Xo + TX + HX, WW);   // sxlo/sxhi multiples of 4
    const int Ws   = sxhi - sxlo;             // 36 or 40
    const int sylo = max(Yo - HY, 0);
    const int syhi = min(Yo + TY + HY, HH);
    const int Rs   = syhi - sylo;             // 19..22

    __shared__ float lds[SLOTS * PLANE_LDS];
    const float* __restrict__ sbase = src + (size_t)b * CC * NN;

    // staging jobs: 440 float4 slots per plane (2ch x 22rows x 10 cols).
    // ch = tid>>8 keeps each wave's LDS destinations contiguous.
    int goff = 0, loff = 0; bool vA = false;
    {
        const int ch = tid >> 8;              // 0..1
        const int r  = tid & 255;             // 0..255, valid < 220
        const int yy = r / 10;
        const int xs = r - yy * 10;
        vA   = (r < ROWS * 10) && (yy < Rs) && (xs * 4 < Ws);
        goff = ch * NN + (sylo + yy) * WW + sxlo + xs * 4;
        loff = ch * PLANE_CH + yy * RSTR + xs * 4;
    }

    // prologue: stage read-window planes for z=Z0: [Z0-4, Z0+5] clipped
    const int qmax = min(DD - 1, Z0 + CZ - 1 + HZ + 1);   // last plane ever read
    for (int q = max(Z0 - HZ, 0); q <= min(Z0 + HZ + 1, DD - 1); ++q) {
        if (vA) *(float4*)(lds + (q % SLOTS) * PLANE_LDS + loff) =
                *(const float4*)(sbase + (size_t)q * HW_ + goff);
    }
    // depth-2 prefetch: issue plane Z0+6 now; ds_write it at iter Z0
    float4 preg{};
    {
        const int p0 = Z0 + HZ + 2;
        if (p0 <= qmax && vA)
            preg = *(const float4*)(sbase + (size_t)p0 * HW_ + goff);
    }

    const size_t fbase = (size_t)b * 3 * NN + (size_t)y * WW + x;
    const size_t obase = (size_t)b * CC * NN + (size_t)y * WW + x;

    for (int z = Z0; z < Z0 + CZ; ++z) {
        __syncthreads();   // prev iter's reads done; this iter's window complete

        // write last iteration's prefetched plane (z+HZ+2) into its slot.
        // slot (z+6)%11 == (z-5)%11 is outside read window [z-4, z+5]: no race.
        const int wp = z + HZ + 2;
        if (wp <= qmax && vA)
            *(float4*)(lds + (wp % SLOTS) * PLANE_LDS + loff) = preg;

        // issue next prefetch (plane z+HZ+3); lands during this iter's compute
        const int np = wp + 1;
        if (np <= qmax && vA)
            preg = *(const float4*)(sbase + (size_t)np * HW_ + goff);

        // --- flow + weights
        const float* fl = flow + fbase + (size_t)z * HW_;
        const float fzv = __builtin_nontemporal_load(fl);
        const float fyv = __builtin_nontemporal_load(fl + NN);
        const float fxv = __builtin_nontemporal_load(fl + 2 * (size_t)NN);
        const float zc = (float)z + fzv;
        const float yc = (float)y + fyv;
        const float xc = (float)x + fxv;

        const float z0f = floorf(zc), y0f = floorf(yc), x0f = floorf(xc);
        const float fz = zc - z0f, fy = yc - y0f, fx = xc - x0f;
        const int z0 = (int)z0f, y0 = (int)y0f, x0 = (int)x0f;
        const int z1 = z0 + 1, y1 = y0 + 1, x1 = x0 + 1;

        const float wz0 = (z0 >= 0 && z0 < DD) ? (1.0f - fz) : 0.0f;
        const float wz1 = (z1 >= 0 && z1 < DD) ? fz : 0.0f;
        const float wy0 = (y0 >= 0 && y0 < HH) ? (1.0f - fy) : 0.0f;
        const float wy1 = (y1 >= 0 && y1 < HH) ? fy : 0.0f;
        const float wx0 = (x0 >= 0 && x0 < WW) ? (1.0f - fx) : 0.0f;
        const float wx1 = (x1 >= 0 && x1 < WW) ? fx : 0.0f;

        const int z0c = min(max(z0, 0), DD - 1), z1c = min(max(z1, 0), DD - 1);
        const int y0c = min(max(y0, 0), HH - 1), y1c = min(max(y1, 0), HH - 1);
        const int x0c = min(max(x0, 0), WW - 1), x1c = min(max(x1, 0), WW - 1);
        const int xb  = min(max(x0, 0), WW - 2);

        const float q0 = (x0c == xb ? wx0 : 0.0f) + (x1c == xb ? wx1 : 0.0f);
        const float q1 = (wx0 + wx1) - q0;
        const float w00 = wz0 * wy0, w01 = wz0 * wy1, w10 = wz1 * wy0, w11 = wz1 * wy1;
        const float w00q0 = w00 * q0, w00q1 = w00 * q1;
        const float w01q0 = w01 * q0, w01q1 = w01 * q1;
        const float w10q0 = w10 * q0, w10q1 = w10 * q1;
        const float w11q0 = w11 * q0, w11q1 = w11 * q1;

        // in-tile test on CLAMPED coords vs staged bounds (edge voxels stay
        // on the LDS path; only interior |flow| outliers fall back)
        const bool inTile = (z0c >= z - HZ) & (z1c <= z + HZ + 1) &
                            (y0c >= sylo) & (y1c < syhi) &
                            (xb >= sxlo) & (xb < sxhi - 1);

        float acc0, acc1;
        if (inTile) {
            const int slot0 = z0c % SLOTS;
            int slot1 = slot0 + (z1c - z0c);
            slot1 = (slot1 == SLOTS) ? 0 : slot1;
            const int yi0 = y0c - sylo, yi1 = y1c - sylo;
            const int xi  = xb - sxlo;
            const int i00 = slot0 * PLANE_LDS + yi0 * RSTR + xi;
            const int i01 = slot0 * PLANE_LDS + yi1 * RSTR + xi;
            const int i10 = slot1 * PLANE_LDS + yi0 * RSTR + xi;
            const int i11 = slot1 * PLANE_LDS + yi1 * RSTR + xi;

            const float a00x = lds[i00],            a00y = lds[i00 + 1];
            const float a01x = lds[i01],            a01y = lds[i01 + 1];
            const float a10x = lds[i10],            a10y = lds[i10 + 1];
            const float a11x = lds[i11],            a11y = lds[i11 + 1];
            const float b00x = lds[i00 + PLANE_CH], b00y = lds[i00 + PLANE_CH + 1];
            const float b01x = lds[i01 + PLANE_CH], b01y = lds[i01 + PLANE_CH + 1];
            const float b10x = lds[i10 + PLANE_CH], b10y = lds[i10 + PLANE_CH + 1];
            const float b11x = lds[i11 + PLANE_CH], b11y = lds[i11 + PLANE_CH + 1];

            acc0 = a00x * w00q0 + a00y * w00q1 + a01x * w01q0 + a01y * w01q1 +
                   a10x * w10q0 + a10y * w10q1 + a11x * w11q0 + a11y * w11q1;
            acc1 = b00x * w00q0 + b00y * w00q1 + b01x * w01q0 + b01y * w01q1 +
                   b10x * w10q0 + b10y * w10q1 + b11x * w11q0 + b11y * w11q1;
        } else {
            // rare interior outlier: direct global gather (identical math)
            const int r00 = (z0c * HH + y0c) * WW + xb;
            const int r01 = (z0c * HH + y1c) * WW + xb;
            const int r10 = (z1c * HH + y0c) * WW + xb;
            const int r11 = (z1c * HH + y1c) * WW + xb;
            const float* s1p = sbase + NN;
            const f2u a00 = *(const f2u*)(sbase + r00);
            const f2u a01 = *(const f2u*)(sbase + r01);
            const f2u a10 = *(const f2u*)(sbase + r10);
            const f2u a11 = *(const f2u*)(sbase + r11);
            const f2u c00 = *(const f2u*)(s1p + r00);
            const f2u c01 = *(const f2u*)(s1p + r01);
            const f2u c10 = *(const f2u*)(s1p + r10);
            const f2u c11 = *(const f2u*)(s1p + r11);
            acc0 = a00.x * w00q0 + a00.y * w00q1 + a01.x * w01q0 + a01.y * w01q1 +
                   a10.x * w10q0 + a10.y * w10q1 + a11.x * w11q0 + a11.y * w11q1;
            acc1 = c00.x * w00q0 + c00.y * w00q1 + c01.x * w01q0 + c01.y * w01q1 +
                   c10.x * w10q0 + c10.y * w10q1 + c11.x * w11q0 + c11.y * w11q1;
        }

        float* o = out + obase + (size_t)z * HW_;
        __builtin_nontemporal_store(acc0, o);
        __builtin_nontemporal_store(acc1, o + NN);
    }
}

extern "C" void kernel_launch(void* const* d_in, const int* in_sizes, int n_in,
                              void* d_out, int out_size, void* d_ws, size_t ws_size,
                              hipStream_t stream) {
    const float* src  = (const float*)d_in[0];
    const float* flow = (const float*)d_in[1];
    float* out = (float*)d_out;

    dim3 grid(5 * 12, DD / CZ, BB);   // 60 xy-tiles, 8 z-chunks, 2 batches = 960 blocks
    dim3 block(TX * TY);              // 512
    st_warp3d_tiled2<<<grid, block, 0, stream>>>(src, flow, out);
}